// Round 1
// baseline (303.006 us; speedup 1.0000x reference)
//
#include <hip/hip_runtime.h>

#define NTOK 16384
#define DIM 512
#define NTAU 4

typedef __attribute__((ext_vector_type(4))) float f32x4;
typedef __attribute__((ext_vector_type(8))) short bf16x8;   // 8 bf16 in 4 VGPRs
typedef __attribute__((ext_vector_type(4))) unsigned short u16x4;
typedef __attribute__((ext_vector_type(8))) unsigned short u16x8;

__device__ inline unsigned short f2bf(float f) {
    union { float f; unsigned int u; } v; v.f = f;
    unsigned int u = v.u + 0x7FFFu + ((v.u >> 16) & 1u);  // RNE
    return (unsigned short)(u >> 16);
}

// ---------------- K0: fp32 -> bf16 convert (weights) ----------------
__global__ void convert_f32_bf16(const float* __restrict__ src,
                                 unsigned short* __restrict__ dst, int n4) {
    int i = blockIdx.x * blockDim.x + threadIdx.x;
    if (i < n4) {
        f32x4 v = ((const f32x4*)src)[i];
        u16x4 o;
        o[0] = f2bf(v[0]); o[1] = f2bf(v[1]); o[2] = f2bf(v[2]); o[3] = f2bf(v[3]);
        ((u16x4*)dst)[i] = o;
    }
}

// ---------------- K1: next = A @ W^T + b  (A fp32 [16384,512], W bf16 [512,512]) ----
// BM=128 BN=128 BK=32, 256 thr = 4 waves (2x2), wave computes 64x64 (4x4 frags)
__global__ __launch_bounds__(256, 2) void gemm_next(
    const float* __restrict__ A, const unsigned short* __restrict__ W,
    const float* __restrict__ bias, float* __restrict__ out)
{
    __shared__ unsigned short lA[128][40];
    __shared__ unsigned short lB[128][40];
    const int tid = threadIdx.x;
    const int m0 = blockIdx.y * 128;
    const int n0 = blockIdx.x * 128;
    const int lane = tid & 63;
    const int w = tid >> 6;
    const int wr = w >> 1, wc = w & 1;

    f32x4 acc[4][4];
#pragma unroll
    for (int i = 0; i < 4; i++)
#pragma unroll
        for (int j = 0; j < 4; j++) acc[i][j] = (f32x4){0.f, 0.f, 0.f, 0.f};

    const int arow = tid >> 3;         // 0..31
    const int acol = (tid & 7) * 4;    // fp32 col within tile
    const int brow = tid >> 2;         // 0..63
    const int bcol = (tid & 3) * 8;    // bf16 col within tile

    for (int k0 = 0; k0 < DIM; k0 += 32) {
#pragma unroll
        for (int i = 0; i < 4; i++) {
            int r = arow + 32 * i;
            f32x4 v = *(const f32x4*)(A + (size_t)(m0 + r) * DIM + k0 + acol);
            u16x4 o;
            o[0] = f2bf(v[0]); o[1] = f2bf(v[1]); o[2] = f2bf(v[2]); o[3] = f2bf(v[3]);
            *(u16x4*)&lA[r][acol] = o;
        }
#pragma unroll
        for (int i = 0; i < 2; i++) {
            int r = brow + 64 * i;
            u16x8 v = *(const u16x8*)(W + (size_t)(n0 + r) * DIM + k0 + bcol);
            *(u16x8*)&lB[r][bcol] = v;
        }
        __syncthreads();

        bf16x8 af[4], bfr[4];
#pragma unroll
        for (int i = 0; i < 4; i++)
            af[i] = *(const bf16x8*)&lA[wr * 64 + i * 16 + (lane & 15)][(lane >> 4) * 8];
#pragma unroll
        for (int j = 0; j < 4; j++)
            bfr[j] = *(const bf16x8*)&lB[wc * 64 + j * 16 + (lane & 15)][(lane >> 4) * 8];
#pragma unroll
        for (int i = 0; i < 4; i++)
#pragma unroll
            for (int j = 0; j < 4; j++)
                acc[i][j] = __builtin_amdgcn_mfma_f32_16x16x32_bf16(af[i], bfr[j], acc[i][j], 0, 0, 0);
        __syncthreads();
    }

#pragma unroll
    for (int j = 0; j < 4; j++) {
        int n = n0 + wc * 64 + j * 16 + (lane & 15);
        float bv = bias[n];
#pragma unroll
        for (int i = 0; i < 4; i++) {
            int mbase = m0 + wr * 64 + i * 16 + (lane >> 4) * 4;
#pragma unroll
            for (int r = 0; r < 4; r++)
                out[(size_t)(mbase + r) * DIM + n] = acc[i][j][r] + bv;
        }
    }
}

// ---------------- K2: streaming fuse (dots, softmax, trend, gates) ----------------
__global__ __launch_bounds__(256) void fuse_stream(
    const float* __restrict__ T_t, const float* __restrict__ S_t,
    const float* __restrict__ t_att, const float* __restrict__ s_att,
    const float* __restrict__ t_spatial, const float* __restrict__ s_spatial,
    const float* __restrict__ t_next, const float* __restrict__ s_next,
    unsigned short* __restrict__ Tf, unsigned short* __restrict__ Sf)
{
    const int lane = threadIdx.x & 63;
    const int wave = blockIdx.x * (blockDim.x >> 6) + (threadIdx.x >> 6);
    const int nwaves = gridDim.x * (blockDim.x >> 6);
    const float scale = 0.04419417382415922f;  // 1/sqrt(512)

    for (int n = wave; n < NTOK; n += nwaves) {
        const size_t rb = (size_t)n * DIM;
        const int c0 = lane * 4, c1 = 256 + lane * 4;
        f32x4 tn_a = *(const f32x4*)(t_next + rb + c0);
        f32x4 tn_b = *(const f32x4*)(t_next + rb + c1);
        f32x4 sn_a = *(const f32x4*)(s_next + rb + c0);
        f32x4 sn_b = *(const f32x4*)(s_next + rb + c1);

        float dws[NTAU], dwt[NTAU];
#pragma unroll
        for (int k = 0; k < NTAU; k++) {
            const size_t kb = ((size_t)k * NTOK + n) * DIM;
            f32x4 sa = *(const f32x4*)(s_att + kb + c0);
            f32x4 sb = *(const f32x4*)(s_att + kb + c1);
            f32x4 ta = *(const f32x4*)(t_spatial + kb + c0);
            f32x4 tb = *(const f32x4*)(t_spatial + kb + c1);
            dws[k] = sa[0]*sn_a[0]+sa[1]*sn_a[1]+sa[2]*sn_a[2]+sa[3]*sn_a[3]
                   + sb[0]*sn_b[0]+sb[1]*sn_b[1]+sb[2]*sn_b[2]+sb[3]*sn_b[3];
            dwt[k] = ta[0]*tn_a[0]+ta[1]*tn_a[1]+ta[2]*tn_a[2]+ta[3]*tn_a[3]
                   + tb[0]*tn_b[0]+tb[1]*tn_b[1]+tb[2]*tn_b[2]+tb[3]*tn_b[3];
        }
#pragma unroll
        for (int k = 0; k < NTAU; k++) {
            float v = dws[k];
#pragma unroll
            for (int off = 32; off; off >>= 1) v += __shfl_xor(v, off);
            dws[k] = v * scale;
            float u = dwt[k];
#pragma unroll
            for (int off = 32; off; off >>= 1) u += __shfl_xor(u, off);
            dwt[k] = u * scale;
        }
        float ms = fmaxf(fmaxf(dws[0], dws[1]), fmaxf(dws[2], dws[3]));
        float mt = fmaxf(fmaxf(dwt[0], dwt[1]), fmaxf(dwt[2], dwt[3]));
        float ws_[NTAU], wt_[NTAU], ssum = 0.f, tsum = 0.f;
#pragma unroll
        for (int k = 0; k < NTAU; k++) {
            ws_[k] = __expf(dws[k] - ms); ssum += ws_[k];
            wt_[k] = __expf(dwt[k] - mt); tsum += wt_[k];
        }
        float rs = 1.f / ssum, rt = 1.f / tsum;
#pragma unroll
        for (int k = 0; k < NTAU; k++) { ws_[k] *= rs; wt_[k] *= rt; }

        f32x4 Tta = {0,0,0,0}, Ttb = {0,0,0,0}, Sta = {0,0,0,0}, Stb = {0,0,0,0};
#pragma unroll
        for (int k = 0; k < NTAU; k++) {
            const size_t kb = ((size_t)k * NTOK + n) * DIM;
            f32x4 ta = *(const f32x4*)(t_att + kb + c0);
            f32x4 tb = *(const f32x4*)(t_att + kb + c1);
            f32x4 sa = *(const f32x4*)(s_spatial + kb + c0);
            f32x4 sb = *(const f32x4*)(s_spatial + kb + c1);
            float wk = ws_[k], vk = wt_[k];
#pragma unroll
            for (int e = 0; e < 4; e++) {
                Tta[e] += wk * ta[e]; Ttb[e] += wk * tb[e];
                Sta[e] += vk * sa[e]; Stb[e] += vk * sb[e];
            }
        }
        f32x4 Ta = *(const f32x4*)(T_t + rb + c0);
        f32x4 Tb = *(const f32x4*)(T_t + rb + c1);
        f32x4 Sa = *(const f32x4*)(S_t + rb + c0);
        f32x4 Sb = *(const f32x4*)(S_t + rb + c1);

        u16x4 oTa, oTb, oSa, oSb;
#pragma unroll
        for (int e = 0; e < 4; e++) {
            float gt_a = 1.f / (1.f + __expf(-tn_a[e]));
            float gt_b = 1.f / (1.f + __expf(-tn_b[e]));
            float gs_a = 1.f / (1.f + __expf(-sn_a[e]));
            float gs_b = 1.f / (1.f + __expf(-sn_b[e]));
            oTa[e] = f2bf(Ta[e] * gt_a + (1.f - gt_a) * Tta[e]);
            oTb[e] = f2bf(Tb[e] * gt_b + (1.f - gt_b) * Ttb[e]);
            oSa[e] = f2bf(Sa[e] * gs_a + (1.f - gs_a) * Sta[e]);
            oSb[e] = f2bf(Sb[e] * gs_b + (1.f - gs_b) * Stb[e]);
        }
        *(u16x4*)(Tf + rb + c0) = oTa;
        *(u16x4*)(Tf + rb + c1) = oTb;
        *(u16x4*)(Sf + rb + c0) = oSa;
        *(u16x4*)(Sf + rb + c1) = oSb;
    }
}

// ---------------- K3: fused final GEMM + epilogue -> d_out ----------------
// Per block: 128 rows x 32 j-cols; 6 GEMM outputs (Wt/Ws x {g,t,s} offsets), K=512
__global__ __launch_bounds__(256, 2) void gemm_final(
    const unsigned short* __restrict__ Tf, const unsigned short* __restrict__ Sf,
    const unsigned short* __restrict__ Wt, const unsigned short* __restrict__ Ws,
    const float* __restrict__ bt, const float* __restrict__ bs,
    float* __restrict__ out)
{
    __shared__ unsigned short lT[128][40];
    __shared__ unsigned short lS[128][40];
    __shared__ unsigned short lW[6][32][40];
    const int tid = threadIdx.x;
    const int m0 = blockIdx.y * 128;
    const int j0 = blockIdx.x * 32;
    const int lane = tid & 63;
    const int w = tid >> 6, wr = w >> 1, wc = w & 1;

    f32x4 acc[6][4];
#pragma unroll
    for (int g = 0; g < 6; g++)
#pragma unroll
        for (int i = 0; i < 4; i++) acc[g][i] = (f32x4){0.f, 0.f, 0.f, 0.f};

    const int arow = tid >> 2;        // 0..63
    const int acol = (tid & 3) * 8;   // bf16 col

    for (int k0 = 0; k0 < DIM; k0 += 32) {
#pragma unroll
        for (int i = 0; i < 2; i++) {
            int r = arow + 64 * i;
            *(u16x8*)&lT[r][acol] = *(const u16x8*)(Tf + (size_t)(m0 + r) * DIM + k0 + acol);
            *(u16x8*)&lS[r][acol] = *(const u16x8*)(Sf + (size_t)(m0 + r) * DIM + k0 + acol);
        }
#pragma unroll
        for (int i = 0; i < 3; i++) {
            int c = tid + 256 * i;          // 0..767
            int g = c >> 7;                 // 6 tiles of 128 chunks
            int rr = (c >> 2) & 31;
            int ch = (c & 3) * 8;
            const unsigned short* src = (g < 3) ? Wt : Ws;
            int row = (g % 3) * DIM + j0 + rr;
            *(u16x8*)&lW[g][rr][ch] = *(const u16x8*)(src + (size_t)row * DIM + k0 + ch);
        }
        __syncthreads();

        bf16x8 aT[4], aS[4];
#pragma unroll
        for (int i = 0; i < 4; i++) {
            aT[i] = *(const bf16x8*)&lT[wr * 64 + i * 16 + (lane & 15)][(lane >> 4) * 8];
            aS[i] = *(const bf16x8*)&lS[wr * 64 + i * 16 + (lane & 15)][(lane >> 4) * 8];
        }
#pragma unroll
        for (int g = 0; g < 6; g++) {
            bf16x8 bw = *(const bf16x8*)&lW[g][wc * 16 + (lane & 15)][(lane >> 4) * 8];
#pragma unroll
            for (int i = 0; i < 4; i++)
                acc[g][i] = __builtin_amdgcn_mfma_f32_16x16x32_bf16(
                    (g < 3) ? aT[i] : aS[i], bw, acc[g][i], 0, 0, 0);
        }
        __syncthreads();
    }

    const int j = j0 + wc * 16 + (lane & 15);
    const float btg = bt[j], btt = bt[512 + j], bts = bt[1024 + j];
    const float bsg = bs[j], bst = bs[512 + j], bss = bs[1024 + j];
#pragma unroll
    for (int i = 0; i < 4; i++) {
        int mbase = m0 + wr * 64 + i * 16 + (lane >> 4) * 4;
#pragma unroll
        for (int r = 0; r < 4; r++) {
            float TG = acc[0][i][r] + btg;
            float TT = acc[1][i][r] + btt;
            float TS = acc[2][i][r] + bts;
            float SG = acc[3][i][r] + bsg;
            float ST = acc[4][i][r] + bst;
            float SS = acc[5][i][r] + bss;
            float gT = 1.f / (1.f + __expf(-TG));
            float gS = 1.f / (1.f + __expf(-SG));
            size_t m = (size_t)(mbase + r);
            out[m * DIM + j] = gT * TT + (1.f - gT) * ST;
            out[(size_t)NTOK * DIM + m * DIM + j] = gS * SS + (1.f - gS) * TS;
        }
    }
}

extern "C" void kernel_launch(void* const* d_in, const int* in_sizes, int n_in,
                              void* d_out, int out_size, void* d_ws, size_t ws_size,
                              hipStream_t stream) {
    const float* T_t       = (const float*)d_in[0];
    const float* S_t       = (const float*)d_in[1];
    const float* t_att     = (const float*)d_in[2];
    const float* s_att     = (const float*)d_in[3];
    const float* t_spatial = (const float*)d_in[4];
    const float* s_spatial = (const float*)d_in[5];
    const float* W_t  = (const float*)d_in[6];
    const float* b_t  = (const float*)d_in[7];
    const float* W_tn = (const float*)d_in[8];
    const float* b_tn = (const float*)d_in[9];
    const float* W_s  = (const float*)d_in[10];
    const float* b_s  = (const float*)d_in[11];
    const float* W_sn = (const float*)d_in[12];
    const float* b_sn = (const float*)d_in[13];
    float* out = (float*)d_out;

    char* ws = (char*)d_ws;
    float*          t_next = (float*)(ws + 0);
    float*          s_next = (float*)(ws + 33554432);
    unsigned short* Tf     = (unsigned short*)(ws + 67108864);
    unsigned short* Sf     = (unsigned short*)(ws + 83886080);
    unsigned short* Wtn_b  = (unsigned short*)(ws + 100663296);
    unsigned short* Wsn_b  = (unsigned short*)(ws + 101187584);
    unsigned short* Wt_b   = (unsigned short*)(ws + 101711872);
    unsigned short* Ws_b   = (unsigned short*)(ws + 103284736);

    const int n_sq = 512 * 512 / 4, n_big = 1536 * 512 / 4;
    convert_f32_bf16<<<(n_sq + 255) / 256, 256, 0, stream>>>(W_tn, Wtn_b, n_sq);
    convert_f32_bf16<<<(n_sq + 255) / 256, 256, 0, stream>>>(W_sn, Wsn_b, n_sq);
    convert_f32_bf16<<<(n_big + 255) / 256, 256, 0, stream>>>(W_t, Wt_b, n_big);
    convert_f32_bf16<<<(n_big + 255) / 256, 256, 0, stream>>>(W_s, Ws_b, n_big);

    dim3 g1(DIM / 128, NTOK / 128);
    gemm_next<<<g1, 256, 0, stream>>>(T_t, Wtn_b, b_tn, t_next);
    gemm_next<<<g1, 256, 0, stream>>>(S_t, Wsn_b, b_sn, s_next);

    fuse_stream<<<2048, 256, 0, stream>>>(T_t, S_t, t_att, s_att, t_spatial, s_spatial,
                                          t_next, s_next, Tf, Sf);

    dim3 g3(DIM / 32, NTOK / 128);
    gemm_final<<<g3, 256, 0, stream>>>(Tf, Sf, Wt_b, Ws_b, b_t, b_s, out);
}